// Round 14
// baseline (178.910 us; speedup 1.0000x reference)
//
#include <hip/hip_runtime.h>
#include <hip/hip_bf16.h>

typedef __attribute__((ext_vector_type(8))) short bf16x8;
typedef __attribute__((ext_vector_type(4))) float f32x4;
typedef __attribute__((ext_vector_type(4))) unsigned short u16x4;

__device__ __forceinline__ unsigned short f2bf(float f) {
    union { float f; unsigned int i; } x; x.f = f;
    unsigned int lsb = (x.i >> 16) & 1u;
    x.i += 0x7fffu + lsb;  // round-to-nearest-even
    return (unsigned short)(x.i >> 16);
}

// async global->LDS DMA, 16B per lane; lds ptr wave-uniform, HW adds lane*16
__device__ __forceinline__ void gl_lds16(const unsigned short* g, unsigned short* l) {
    __builtin_amdgcn_global_load_lds(
        (const __attribute__((address_space(1))) void*)g,
        (__attribute__((address_space(3))) void*)l, 16, 0, 0);
}

__device__ __forceinline__ unsigned int cvt_pk_bf16(float lo, float hi) {
    unsigned int d;
    asm("v_cvt_pk_bf16_f32 %0, %1, %2" : "=v"(d) : "v"(lo), "v"(hi));
    return d;
}

// In-register 16x32 C-fragment transpose -> A-frag/store layout (attn-verified).
// Input: pa = C-frag rows 0..15 of a 32-row span (per-lane row=kg*4+r, col=ln15),
//        pb = rows 16..31. Output: lane (kg,ln15) holds bf16 of rows kg*8..kg*8+7
// at fixed col=ln15 -> one contiguous 16B run along the row direction.
__device__ __forceinline__ bf16x8 pf_build_s(f32x4 pa, f32x4 pb, float s) {
    unsigned int E0 = cvt_pk_bf16(pa[0] * s, pa[1] * s);
    unsigned int O0 = cvt_pk_bf16(pa[2] * s, pa[3] * s);
    unsigned int E1 = cvt_pk_bf16(pb[0] * s, pb[1] * s);
    unsigned int O1 = cvt_pk_bf16(pb[2] * s, pb[3] * s);
    asm("v_permlane32_swap_b32 %0, %1" : "+v"(E0), "+v"(E1));
    asm("v_permlane32_swap_b32 %0, %1" : "+v"(O0), "+v"(O1));
    asm("v_permlane16_swap_b32 %0, %1" : "+v"(E0), "+v"(E1));
    asm("v_permlane16_swap_b32 %0, %1" : "+v"(O0), "+v"(O1));
    union { unsigned int u[4]; bf16x8 v; } r;
    r.u[0] = E0; r.u[1] = O0; r.u[2] = E1; r.u[3] = O1;
    return r.v;
}

// ---------------------------------------------------------------------------
// fused preprocessing v2:
//   blocks [0,4096)    : fp32->bf16 convert of x (f32x4 in, u16x4 out)
//   blocks [4096,5120) : 64x64 transpose+convert tiles of the 4 weights,
//                        f32x4 loads (256B/16-lane segments), LDS [64][65]
//                        f32 (pad -> ~2-way conflicts), bf16x8 stores
//                        (128B/8-lane contiguous runs). Replaces the scalar
//                        32x32 tconv (4B loads / 2B stores, ~2x slower).
// Output mapping unchanged: dst[n][k] = W[k][n].
// ---------------------------------------------------------------------------
__global__ __launch_bounds__(256) void prep(
    const float* __restrict__ x,
    const float* __restrict__ Wq, const float* __restrict__ Wk,
    const float* __restrict__ Wv, const float* __restrict__ Wo,
    unsigned short* __restrict__ xb,
    unsigned short* __restrict__ WqkvT, unsigned short* __restrict__ WoT)
{
    const int E = 1024;
    const int bid = blockIdx.x;
    const int tid = threadIdx.x;
    __shared__ float t64[64][65];

    if (bid < 4096) {                       // x convert: 4096*256*4 = 4M elems
        int i = bid * 256 + tid;
        f32x4 v = ((const f32x4*)x)[i];
        u16x4 o;
#pragma unroll
        for (int j = 0; j < 4; ++j) o[j] = f2bf(v[j]);
        ((u16x4*)xb)[i] = o;
        return;
    }
    const int r = bid - 4096;               // 0..1023
    const int which = r >> 8;               // 0..3 : Wq,Wk,Wv,Wo (256 tiles ea)
    const int sub = r & 255;
    const float* src = which == 0 ? Wq : which == 1 ? Wk : which == 2 ? Wv : Wo;
    unsigned short* dst = which == 3 ? WoT : WqkvT + (size_t)which * E * E;

    const int n0 = (sub & 15) * 64, k0 = (sub >> 4) * 64;

    // load: thread (lr, lc) covers rows k0+lr+16i, cols n0+lc..lc+3
    const int lr = tid >> 4;                // 0..15
    const int lc = (tid & 15) * 4;          // 0..60
#pragma unroll
    for (int i = 0; i < 4; ++i) {
        f32x4 v = *(const f32x4*)(src + (size_t)(k0 + lr + 16 * i) * E + n0 + lc);
        t64[lr + 16 * i][lc + 0] = v[0];
        t64[lr + 16 * i][lc + 1] = v[1];
        t64[lr + 16 * i][lc + 2] = v[2];
        t64[lr + 16 * i][lc + 3] = v[3];
    }
    __syncthreads();

    // store: thread (nn, kk) writes dst[n0+nn+32p][k0+kk..kk+7] (16B bf16x8)
    const int nn = tid >> 3;                // 0..31
    const int kk = (tid & 7) * 8;           // 0..56
#pragma unroll
    for (int p = 0; p < 2; ++p) {
        const int n = nn + 32 * p;
        bf16x8 o;
#pragma unroll
        for (int j = 0; j < 8; ++j) o[j] = f2bf(t64[kk + j][n]);
        *(bf16x8*)(dst + (size_t)(n0 + n) * E + k0 + kk) = o;
    }
}

// ---------------------------------------------------------------------------
// m97-style GEMM (QKV): C = A[M,K] @ BT[N,K]^T, bf16 in, fp32 acc. 128x128
// tile, BK=32, 256 thr = 4 waves 2x2; 16 MFMA + 8 ds_read_b128 per
// K-step/wave; staging via global_load_lds dwordx4.
//
// R12 post-mortem: retiling QKV to 64x64 cost +13 us (q/k 16B-store epilogue
// scatters at stride 128B; 8 blocks/CU at N=3072 thrashes L2). The 64x64
// structure's win is shape-specific to out-proj. This 128x128 kernel
// (586 TF, 3 blocks/CU) is the verified best for QKV.
// ---------------------------------------------------------------------------
template <int PERM>
__global__ __launch_bounds__(256) void gemm128(
    const unsigned short* __restrict__ A,
    const unsigned short* __restrict__ BT,
    const float* __restrict__ bias,
    float* __restrict__ Cf,
    unsigned short* __restrict__ q_out,
    unsigned short* __restrict__ k_out,
    unsigned short* __restrict__ v_out,   // [bh][64][T] transposed
    int M, int N, int K)
{
    __shared__ __align__(16) unsigned short As[128 * 32];
    __shared__ __align__(16) unsigned short Bs[128 * 32];

    const int tid  = threadIdx.x;
    const int wave = tid >> 6;
    const int lane = tid & 63;
    const int ln15 = lane & 15;
    const int kg   = lane >> 4;
    const int bm = blockIdx.x * 128, bn = blockIdx.y * 128;
    const int wm = (wave >> 1) * 64, wn = (wave & 1) * 64;

    f32x4 acc[4][4];
#pragma unroll
    for (int i = 0; i < 4; ++i)
#pragma unroll
        for (int j = 0; j < 4; ++j) acc[i][j] = (f32x4){0.f, 0.f, 0.f, 0.f};

    const int sr = wave * 32 + (lane >> 2);
    const int sc = (lane & 3) * 8;

    for (int k0 = 0; k0 < K; k0 += 32) {
        gl_lds16(A  + (size_t)(bm + sr)      * K + k0 + sc, As + wave * 1024);
        gl_lds16(A  + (size_t)(bm + sr + 16) * K + k0 + sc, As + wave * 1024 + 512);
        gl_lds16(BT + (size_t)(bn + sr)      * K + k0 + sc, Bs + wave * 1024);
        gl_lds16(BT + (size_t)(bn + sr + 16) * K + k0 + sc, Bs + wave * 1024 + 512);
        __syncthreads();

        bf16x8 af[4], bw[4];
#pragma unroll
        for (int mt = 0; mt < 4; ++mt)
            af[mt] = *(const bf16x8*)&As[(wm + mt * 16 + ln15) * 32 + kg * 8];
#pragma unroll
        for (int nt = 0; nt < 4; ++nt)
            bw[nt] = *(const bf16x8*)&Bs[(wn + nt * 16 + ln15) * 32 + kg * 8];
        if (PERM == 0) {   // compile-time: C^T fragments (unused instantiation)
#pragma unroll
            for (int mt = 0; mt < 4; ++mt)
#pragma unroll
                for (int nt = 0; nt < 4; ++nt)
                    acc[mt][nt] = __builtin_amdgcn_mfma_f32_16x16x32_bf16(
                        bw[nt], af[mt], acc[mt][nt], 0, 0, 0);
        } else {           // compile-time: C fragments
#pragma unroll
            for (int mt = 0; mt < 4; ++mt)
#pragma unroll
                for (int nt = 0; nt < 4; ++nt)
                    acc[mt][nt] = __builtin_amdgcn_mfma_f32_16x16x32_bf16(
                        af[mt], bw[nt], acc[mt][nt], 0, 0, 0);
        }
        __syncthreads();
    }

    if (PERM == 0) {
#pragma unroll
        for (int mt = 0; mt < 4; ++mt) {
            const int row = bm + wm + mt * 16 + ln15;
#pragma unroll
            for (int nt = 0; nt < 4; ++nt) {
                const int c0 = bn + wn + nt * 16 + kg * 4;
                f32x4 bv = *(const f32x4*)(bias + c0);
                f32x4 o;
#pragma unroll
                for (int r = 0; r < 4; ++r) o[r] = acc[mt][nt][r] + bv[r];
                *(f32x4*)(Cf + (size_t)row * N + c0) = o;
            }
        }
    } else {
        const int sec = bn >> 10;
        if (sec < 2) {
            unsigned short* dst = sec == 0 ? q_out : k_out;
            const float scale = sec == 0 ? 0.125f : 1.0f;  // q pre-scale (pow2)
#pragma unroll
            for (int nt = 0; nt < 4; ++nt) {
                const int col = bn + wn + nt * 16 + ln15;
                const int h = (col >> 6) & 15, d = col & 63;
#pragma unroll
                for (int mt = 0; mt < 4; ++mt) {
#pragma unroll
                    for (int r = 0; r < 4; ++r) {
                        const int row = bm + wm + mt * 16 + kg * 4 + r;
                        const int b = row >> 11, t = row & 2047;
                        dst[((size_t)(b * 16 + h) * 2048 + t) * 64 + d] =
                            f2bf(acc[mt][nt][r] * scale);
                    }
                }
            }
        } else {
            // unswapped; pf_build over mt-pairs -> writes vT[bh][d][t] directly
#pragma unroll
            for (int nt = 0; nt < 4; ++nt) {
                const int c = bn + wn + nt * 16 + ln15;
                const int h = (c >> 6) & 15, d = c & 63;
#pragma unroll
                for (int mp = 0; mp < 2; ++mp) {
                    const int t0 = bm + wm + mp * 32 + kg * 8;
                    const int b = t0 >> 11, t = t0 & 2047;
                    bf16x8 pf = pf_build_s(acc[2 * mp][nt], acc[2 * mp + 1][nt], 1.0f);
                    *(bf16x8*)(v_out + ((size_t)(b * 16 + h) * 64 + d) * 2048 + t) = pf;
                }
            }
        }
    }
}

// ---------------------------------------------------------------------------
// out-projection GEMM, 64x64 tile (1024 blocks = 4/CU). R10-verified; the
// 64x64 structure stays HERE only (R12: it does not transfer to QKV).
// ---------------------------------------------------------------------------
__global__ __launch_bounds__(256) void gemm_op(
    const unsigned short* __restrict__ A,
    const unsigned short* __restrict__ BT,
    const float* __restrict__ bias,
    float* __restrict__ Cf,
    int M, int N, int K)
{
    __shared__ __align__(16) unsigned short As[64 * 32];
    __shared__ __align__(16) unsigned short Bs[64 * 32];

    const int tid  = threadIdx.x;
    const int wave = tid >> 6;
    const int lane = tid & 63;
    const int ln15 = lane & 15;
    const int kg   = lane >> 4;
    const int bm = blockIdx.x * 64, bn = blockIdx.y * 64;
    const int wm = (wave >> 1) * 32, wn = (wave & 1) * 32;

    f32x4 acc[2][2];
#pragma unroll
    for (int i = 0; i < 2; ++i)
#pragma unroll
        for (int j = 0; j < 2; ++j) acc[i][j] = (f32x4){0.f, 0.f, 0.f, 0.f};

    const int sr  = wave * 16 + (lane >> 2);   // stage row 0..63
    const int scl = (lane & 3) * 8;

    for (int k0 = 0; k0 < K; k0 += 32) {
        gl_lds16(A  + (size_t)(bm + sr) * K + k0 + scl, As + wave * 512);
        gl_lds16(BT + (size_t)(bn + sr) * K + k0 + scl, Bs + wave * 512);
        __syncthreads();

        bf16x8 af[2], bw[2];
#pragma unroll
        for (int mt = 0; mt < 2; ++mt)
            af[mt] = *(const bf16x8*)&As[(wm + mt * 16 + ln15) * 32 + kg * 8];
#pragma unroll
        for (int nt = 0; nt < 2; ++nt)
            bw[nt] = *(const bf16x8*)&Bs[(wn + nt * 16 + ln15) * 32 + kg * 8];
#pragma unroll
        for (int mt = 0; mt < 2; ++mt)
#pragma unroll
            for (int nt = 0; nt < 2; ++nt)
                acc[mt][nt] = __builtin_amdgcn_mfma_f32_16x16x32_bf16(
                    bw[nt], af[mt], acc[mt][nt], 0, 0, 0);
        __syncthreads();
    }

    // swapped: acc[mt][nt][r] = C[row=bm+wm+mt*16+ln15][col=bn+wn+nt*16+kg*4+r]
#pragma unroll
    for (int mt = 0; mt < 2; ++mt) {
        const int row = bm + wm + mt * 16 + ln15;
#pragma unroll
        for (int nt = 0; nt < 2; ++nt) {
            const int c0 = bn + wn + nt * 16 + kg * 4;
            f32x4 bv = *(const f32x4*)(bias + c0);
            f32x4 o;
#pragma unroll
            for (int r = 0; r < 4; ++r) o[r] = acc[mt][nt][r] + bv[r];
            *(f32x4*)(Cf + (size_t)row * N + c0) = o;
        }
    }
}

// mask (diagonal block) + exp + in-register transpose + row-sum accumulate
__device__ __forceinline__ void softmax_tile(
    f32x4 sr[4], bool diag, int q_loc, int kg,
    bf16x8& pf0, bf16x8& pf1, f32x4& accl, bf16x8 ones)
{
    if (diag) {
#pragma unroll
        for (int kt = 0; kt < 4; ++kt)
#pragma unroll
            for (int r = 0; r < 4; ++r)
                if (kt * 16 + kg * 4 + r > q_loc) sr[kt][r] = -1e30f;
    }
    f32x4 pe[4];
#pragma unroll
    for (int kt = 0; kt < 4; ++kt)
#pragma unroll
        for (int r = 0; r < 4; ++r) pe[kt][r] = __expf(sr[kt][r]);
    pf0 = pf_build_s(pe[0], pe[1], 1.0f);
    pf1 = pf_build_s(pe[2], pe[3], 1.0f);
    accl = __builtin_amdgcn_mfma_f32_16x16x32_bf16(pf0, ones, accl, 0, 0, 0);
    accl = __builtin_amdgcn_mfma_f32_16x16x32_bf16(pf1, ones, accl, 0, 0, 0);
}

// ---------------------------------------------------------------------------
// MFMA flash attention v6+T5 (causal). LOOP FROZEN -- exact R8/R10-verified
// iteration; R11 XCD-locality block remap kept (R12 counters confirm FETCH
// 55 -> 12.4 MB, near the per-iteration ideal). Paired strips (sA, sB=31-sA,
// 33 iters balanced); K/V staged once, shared; double-buffered LDS; ONE
// barrier/iter; register prefetch; swapped QK^T + in-register P transpose;
// s_setprio(1) around MFMA clusters.
// ---------------------------------------------------------------------------
__global__ __launch_bounds__(256) void flash_attn(
    const unsigned short* __restrict__ Q,
    const unsigned short* __restrict__ Km,
    const unsigned short* __restrict__ Vtg,
    unsigned short* __restrict__ O,
    int T, int H)
{
    __shared__ __align__(16) unsigned short Ks[2][64][72];   // [buf][key][d]
    __shared__ __align__(16) unsigned short Vs[2][64][72];   // [buf][d][key]

    const int tid  = threadIdx.x;
    const int wave = tid >> 6;
    const int lane = tid & 63;
    const int ln15 = lane & 15;
    const int kg   = lane >> 4;

    // XCD-locality remap: flat -> (xcd, slot); 4 heads per XCD, 16 strips each
    const int flat = blockIdx.y * gridDim.x + blockIdx.x;   // 0..511
    const int xcd  = flat & 7;
    const int slot = flat >> 3;                             // 0..63
    const int bh   = xcd * 4 + (slot >> 4);                 // 0..31
    const int sA   = slot & 15;                             // 0..15

    const int sB   = (T >> 6) - 1 - sA;       // 31..16
    const int kmax = sB;
    const int b    = bh >> 4, h = bh & 15;
    const size_t base  = (size_t)bh * T * 64;
    const size_t vbase = (size_t)bh * 64 * T;
    const int q_loc = wave * 16 + ln15;       // query row within strip

    bf16x8 qf[2][2];
    {
        const unsigned short* QrA = Q + base + (size_t)(sA * 64 + q_loc) * 64;
        const unsigned short* QrB = Q + base + (size_t)(sB * 64 + q_loc) * 64;
        qf[0][0] = *(const bf16x8*)(QrA + kg * 8);
        qf[0][1] = *(const bf16x8*)(QrA + 32 + kg * 8);
        qf[1][0] = *(const bf16x8*)(QrB + kg * 8);
        qf[1][1] = *(const bf16x8*)(QrB + 32 + kg * 8);
    }

    bf16x8 ones;
    {
        const short o = (ln15 == 0) ? (short)0x3F80 : (short)0;
#pragma unroll
        for (int j = 0; j < 8; ++j) ones[j] = o;
    }

    f32x4 o_acc[2][4];
#pragma unroll
    for (int s = 0; s < 2; ++s)
#pragma unroll
        for (int dt = 0; dt < 4; ++dt) o_acc[s][dt] = (f32x4){0.f, 0.f, 0.f, 0.f};
    f32x4 acc_l[2] = {(f32x4){0.f, 0.f, 0.f, 0.f}, (f32x4){0.f, 0.f, 0.f, 0.f}};

    const int sky = tid >> 3;             // 0..31
    const int sd  = (tid & 7) * 8;

    bf16x8 pk0, pk1, pv0, pv1;
    pk0 = *(const bf16x8*)(Km + base + (size_t)sky * 64 + sd);
    pk1 = *(const bf16x8*)(Km + base + (size_t)(sky + 32) * 64 + sd);
    pv0 = *(const bf16x8*)(Vtg + vbase + (size_t)sky * T + sd);
    pv1 = *(const bf16x8*)(Vtg + vbase + (size_t)(sky + 32) * T + sd);

    for (int kb = 0; kb <= kmax; ++kb) {
        const int bufi = kb & 1;
        *(bf16x8*)&Ks[bufi][sky][sd]      = pk0;
        *(bf16x8*)&Ks[bufi][sky + 32][sd] = pk1;
        *(bf16x8*)&Vs[bufi][sky][sd]      = pv0;
        *(bf16x8*)&Vs[bufi][sky + 32][sd] = pv1;
        if (kb < kmax) {
            const int kn = (kb + 1) * 64;
            pk0 = *(const bf16x8*)(Km + base + (size_t)(kn + sky) * 64 + sd);
            pk1 = *(const bf16x8*)(Km + base + (size_t)(kn + sky + 32) * 64 + sd);
            pv0 = *(const bf16x8*)(Vtg + vbase + (size_t)sky * T + kn + sd);
            pv1 = *(const bf16x8*)(Vtg + vbase + (size_t)(sky + 32) * T + kn + sd);
        }
        __syncthreads();

        const bool doA = (kb <= sA);

        f32x4 srB[4], srA[4];
        __builtin_amdgcn_s_setprio(1);
#pragma unroll
        for (int kt = 0; kt < 4; ++kt) {
            bf16x8 kf0 = *(const bf16x8*)&Ks[bufi][kt * 16 + ln15][kg * 8];
            bf16x8 kf1 = *(const bf16x8*)&Ks[bufi][kt * 16 + ln15][32 + kg * 8];
            f32x4 a = (f32x4){0.f, 0.f, 0.f, 0.f};
            a = __builtin_amdgcn_mfma_f32_16x16x32_bf16(kf0, qf[1][0], a, 0, 0, 0);
            a = __builtin_amdgcn_mfma_f32_16x16x32_bf16(kf1, qf[1][1], a, 0, 0, 0);
            srB[kt] = a;
            if (doA) {
                f32x4 c = (f32x4){0.f, 0.f, 0.f, 0.f};
                c = __builtin_amdgcn_mfma_f32_16x16x32_bf16(kf0, qf[0][0], c, 0, 0, 0);
                c = __builtin_amdgcn_mfma_f32_16x16x32_bf16(kf1, qf[0][1], c, 0, 0, 0);
                srA[kt] = c;
            }
        }
        __builtin_amdgcn_s_setprio(0);

        bf16x8 pfB0, pfB1, pfA0, pfA1;
        softmax_tile(srB, kb == sB, q_loc, kg, pfB0, pfB1, acc_l[1], ones);
        if (doA)
            softmax_tile(srA, kb == sA, q_loc, kg, pfA0, pfA1, acc_l[0], ones);

        __builtin_amdgcn_s_setprio(1);
#pragma unroll
        for (int dt = 0; dt < 4; ++dt) {
            bf16x8 vf0 = *(const bf16x8*)&Vs[bufi][dt * 16 + ln15][kg * 8];
            bf16x8 vf1 = *(const bf16x8*)&Vs[bufi][dt * 16 + ln15][32 + kg * 8];
            o_acc[1][dt] = __builtin_amdgcn_mfma_f32_16x16x32_bf16(pfB0, vf0, o_acc[1][dt], 0, 0, 0);
            o_acc[1][dt] = __builtin_amdgcn_mfma_f32_16x16x32_bf16(pfB1, vf1, o_acc[1][dt], 0, 0, 0);
            if (doA) {
                o_acc[0][dt] = __builtin_amdgcn_mfma_f32_16x16x32_bf16(pfA0, vf0, o_acc[0][dt], 0, 0, 0);
                o_acc[0][dt] = __builtin_amdgcn_mfma_f32_16x16x32_bf16(pfA1, vf1, o_acc[0][dt], 0, 0, 0);
            }
        }
        __builtin_amdgcn_s_setprio(0);
    }

    // normalize; l for row kg*4+r sits in lane kg*16 (col 0)
#pragma unroll
    for (int s = 0; s < 2; ++s) {
        const int qb = (s == 0 ? sA : sB) * 64;
        float inv[4];
#pragma unroll
        for (int r = 0; r < 4; ++r)
            inv[r] = 1.0f / __shfl(acc_l[s][r], lane & 48, 64);
#pragma unroll
        for (int dt = 0; dt < 4; ++dt)
#pragma unroll
            for (int r = 0; r < 4; ++r) {
                const int t = qb + wave * 16 + kg * 4 + r;
                const int d = dt * 16 + ln15;
                O[(size_t)(b * T + t) * (H * 64) + h * 64 + d] =
                    f2bf(o_acc[s][dt][r] * inv[r]);
            }
    }
}

extern "C" void kernel_launch(void* const* d_in, const int* in_sizes, int n_in,
                              void* d_out, int out_size, void* d_ws, size_t ws_size,
                              hipStream_t stream)
{
    const int B = 2, T = 2048, E = 1024, H = 16;
    const int M = B * T;  // 4096

    const float* x  = (const float*)d_in[0];
    const float* Wq = (const float*)d_in[1];
    const float* Wk = (const float*)d_in[2];
    const float* Wv = (const float*)d_in[3];
    const float* Wo = (const float*)d_in[4];
    const float* bo = (const float*)d_in[5];
    float* out = (float*)d_out;

    // workspace (bf16): xb 8MB, WqkvT 6MB, WoT 2MB, q/k/vT 8MB x3, ao 8MB
    unsigned short* xb     = (unsigned short*)d_ws;
    unsigned short* WqkvT  = xb + (size_t)M * E;            // [3072][1024]
    unsigned short* WoT    = WqkvT + (size_t)3 * E * E;     // [1024][1024]
    unsigned short* q      = WoT + (size_t)E * E;           // [BH][T][64]
    unsigned short* k      = q + (size_t)M * E;
    unsigned short* vT     = k + (size_t)M * E;             // [BH][64][T]
    unsigned short* ao     = vT + (size_t)M * E;            // [M][E]

    // fused convert + 4x weight transpose (vectorized 64x64 tiles)
    prep<<<5120, 256, 0, stream>>>(x, Wq, Wk, Wv, Wo, xb, WqkvT, WoT);

    // fused QKV projection: [4096,1024] @ [1024,3072]; V written transposed
    dim3 g1(M / 128, 3 * E / 128);
    gemm128<1><<<g1, 256, 0, stream>>>(xb, WqkvT, nullptr, nullptr, q, k, vT,
                                       M, 3 * E, E);

    // flash attention: 512 blocks, XCD-locality remapped (frozen v6+T5 loop)
    dim3 ag(T / 128, B * H);
    flash_attn<<<ag, 256, 0, stream>>>(q, k, vT, ao, T, H);

    // out-projection: 64x64 tiles -> 1024 blocks = 4/CU
    dim3 g2(M / 64, E / 64);
    gemm_op<<<g2, 256, 0, stream>>>(ao, WoT, bo, out, M, E, E);
}

// Round 15
// 176.519 us; speedup vs baseline: 1.0135x; 1.0135x over previous
//
#include <hip/hip_runtime.h>
#include <hip/hip_bf16.h>

typedef __attribute__((ext_vector_type(8))) short bf16x8;
typedef __attribute__((ext_vector_type(4))) float f32x4;
typedef __attribute__((ext_vector_type(4))) unsigned short u16x4;

__device__ __forceinline__ unsigned short f2bf(float f) {
    union { float f; unsigned int i; } x; x.f = f;
    unsigned int lsb = (x.i >> 16) & 1u;
    x.i += 0x7fffu + lsb;  // round-to-nearest-even
    return (unsigned short)(x.i >> 16);
}

// async global->LDS DMA, 16B per lane; lds ptr wave-uniform, HW adds lane*16
__device__ __forceinline__ void gl_lds16(const unsigned short* g, unsigned short* l) {
    __builtin_amdgcn_global_load_lds(
        (const __attribute__((address_space(1))) void*)g,
        (__attribute__((address_space(3))) void*)l, 16, 0, 0);
}

__device__ __forceinline__ unsigned int cvt_pk_bf16(float lo, float hi) {
    unsigned int d;
    asm("v_cvt_pk_bf16_f32 %0, %1, %2" : "=v"(d) : "v"(lo), "v"(hi));
    return d;
}

// In-register 16x32 C-fragment transpose -> A-frag/store layout (attn-verified).
// Input: pa = C-frag rows 0..15 of a 32-row span (per-lane row=kg*4+r, col=ln15),
//        pb = rows 16..31. Output: lane (kg,ln15) holds bf16 of rows kg*8..kg*8+7
// at fixed col=ln15 -> one contiguous 16B run along the row direction.
__device__ __forceinline__ bf16x8 pf_build_s(f32x4 pa, f32x4 pb, float s) {
    unsigned int E0 = cvt_pk_bf16(pa[0] * s, pa[1] * s);
    unsigned int O0 = cvt_pk_bf16(pa[2] * s, pa[3] * s);
    unsigned int E1 = cvt_pk_bf16(pb[0] * s, pb[1] * s);
    unsigned int O1 = cvt_pk_bf16(pb[2] * s, pb[3] * s);
    asm("v_permlane32_swap_b32 %0, %1" : "+v"(E0), "+v"(E1));
    asm("v_permlane32_swap_b32 %0, %1" : "+v"(O0), "+v"(O1));
    asm("v_permlane16_swap_b32 %0, %1" : "+v"(E0), "+v"(E1));
    asm("v_permlane16_swap_b32 %0, %1" : "+v"(O0), "+v"(O1));
    union { unsigned int u[4]; bf16x8 v; } r;
    r.u[0] = E0; r.u[1] = O0; r.u[2] = E1; r.u[3] = O1;
    return r.v;
}

// ---------------------------------------------------------------------------
// fused preprocessing: blocks [0,4096) = fp32->bf16 convert of x (x4 vec);
// blocks [4096,8192) = 32x32 transpose+convert of the 4 weight matrices.
// (R14: the vectorized 64x64 variant measured neutral-to-negative; this
// scalar-transpose version is part of the verified-best R11 config.)
// ---------------------------------------------------------------------------
__global__ __launch_bounds__(256) void prep(
    const float* __restrict__ x,
    const float* __restrict__ Wq, const float* __restrict__ Wk,
    const float* __restrict__ Wv, const float* __restrict__ Wo,
    unsigned short* __restrict__ xb,
    unsigned short* __restrict__ WqkvT, unsigned short* __restrict__ WoT)
{
    const int E = 1024;
    const int bid = blockIdx.x;
    __shared__ float t[32][33];

    if (bid < 4096) {                       // x convert: 4096*256*4 = 4M elems
        int i = bid * 256 + threadIdx.x;
        f32x4 v = ((const f32x4*)x)[i];
        u16x4 o;
#pragma unroll
        for (int j = 0; j < 4; ++j) o[j] = f2bf(v[j]);
        ((u16x4*)xb)[i] = o;
        return;
    }
    const int r = bid - 4096;
    const int which = r >> 10;              // 0..3 : Wq,Wk,Wv,Wo
    const int sub = r & 1023;
    const float* src = which == 0 ? Wq : which == 1 ? Wk : which == 2 ? Wv : Wo;
    unsigned short* dst = which == 3 ? WoT : WqkvT + (size_t)which * E * E;

    const int tx = threadIdx.x & 31, ty = threadIdx.x >> 5;  // ty 0..7
    const int n0 = (sub & 31) * 32, k0 = (sub >> 5) * 32;
#pragma unroll
    for (int i = 0; i < 4; ++i)
        t[ty + 8 * i][tx] = src[(size_t)(k0 + ty + 8 * i) * E + n0 + tx];
    __syncthreads();
#pragma unroll
    for (int i = 0; i < 4; ++i)
        dst[(size_t)(n0 + ty + 8 * i) * E + k0 + tx] = f2bf(t[tx][ty + 8 * i]);
}

// ---------------------------------------------------------------------------
// m97-style GEMM (QKV): C = A[M,K] @ BT[N,K]^T, bf16 in, fp32 acc. 128x128
// tile, BK=32, 256 thr = 4 waves 2x2; 16 MFMA + 8 ds_read_b128 per
// K-step/wave; staging via global_load_lds dwordx4. Verified best for the
// QKV shape (R12: 64x64 retile cost +13 us -- do not retile w/o counters).
// ---------------------------------------------------------------------------
template <int PERM>
__global__ __launch_bounds__(256) void gemm128(
    const unsigned short* __restrict__ A,
    const unsigned short* __restrict__ BT,
    const float* __restrict__ bias,
    float* __restrict__ Cf,
    unsigned short* __restrict__ q_out,
    unsigned short* __restrict__ k_out,
    unsigned short* __restrict__ v_out,   // [bh][64][T] transposed
    int M, int N, int K)
{
    __shared__ __align__(16) unsigned short As[128 * 32];
    __shared__ __align__(16) unsigned short Bs[128 * 32];

    const int tid  = threadIdx.x;
    const int wave = tid >> 6;
    const int lane = tid & 63;
    const int ln15 = lane & 15;
    const int kg   = lane >> 4;
    const int bm = blockIdx.x * 128, bn = blockIdx.y * 128;
    const int wm = (wave >> 1) * 64, wn = (wave & 1) * 64;

    f32x4 acc[4][4];
#pragma unroll
    for (int i = 0; i < 4; ++i)
#pragma unroll
        for (int j = 0; j < 4; ++j) acc[i][j] = (f32x4){0.f, 0.f, 0.f, 0.f};

    const int sr = wave * 32 + (lane >> 2);
    const int sc = (lane & 3) * 8;

    for (int k0 = 0; k0 < K; k0 += 32) {
        gl_lds16(A  + (size_t)(bm + sr)      * K + k0 + sc, As + wave * 1024);
        gl_lds16(A  + (size_t)(bm + sr + 16) * K + k0 + sc, As + wave * 1024 + 512);
        gl_lds16(BT + (size_t)(bn + sr)      * K + k0 + sc, Bs + wave * 1024);
        gl_lds16(BT + (size_t)(bn + sr + 16) * K + k0 + sc, Bs + wave * 1024 + 512);
        __syncthreads();

        bf16x8 af[4], bw[4];
#pragma unroll
        for (int mt = 0; mt < 4; ++mt)
            af[mt] = *(const bf16x8*)&As[(wm + mt * 16 + ln15) * 32 + kg * 8];
#pragma unroll
        for (int nt = 0; nt < 4; ++nt)
            bw[nt] = *(const bf16x8*)&Bs[(wn + nt * 16 + ln15) * 32 + kg * 8];
        if (PERM == 0) {   // compile-time: C^T fragments (unused instantiation)
#pragma unroll
            for (int mt = 0; mt < 4; ++mt)
#pragma unroll
                for (int nt = 0; nt < 4; ++nt)
                    acc[mt][nt] = __builtin_amdgcn_mfma_f32_16x16x32_bf16(
                        bw[nt], af[mt], acc[mt][nt], 0, 0, 0);
        } else {           // compile-time: C fragments
#pragma unroll
            for (int mt = 0; mt < 4; ++mt)
#pragma unroll
                for (int nt = 0; nt < 4; ++nt)
                    acc[mt][nt] = __builtin_amdgcn_mfma_f32_16x16x32_bf16(
                        af[mt], bw[nt], acc[mt][nt], 0, 0, 0);
        }
        __syncthreads();
    }

    if (PERM == 0) {
#pragma unroll
        for (int mt = 0; mt < 4; ++mt) {
            const int row = bm + wm + mt * 16 + ln15;
#pragma unroll
            for (int nt = 0; nt < 4; ++nt) {
                const int c0 = bn + wn + nt * 16 + kg * 4;
                f32x4 bv = *(const f32x4*)(bias + c0);
                f32x4 o;
#pragma unroll
                for (int r = 0; r < 4; ++r) o[r] = acc[mt][nt][r] + bv[r];
                *(f32x4*)(Cf + (size_t)row * N + c0) = o;
            }
        }
    } else {
        const int sec = bn >> 10;
        if (sec < 2) {
            unsigned short* dst = sec == 0 ? q_out : k_out;
            const float scale = sec == 0 ? 0.125f : 1.0f;  // q pre-scale (pow2)
#pragma unroll
            for (int nt = 0; nt < 4; ++nt) {
                const int col = bn + wn + nt * 16 + ln15;
                const int h = (col >> 6) & 15, d = col & 63;
#pragma unroll
                for (int mt = 0; mt < 4; ++mt) {
#pragma unroll
                    for (int r = 0; r < 4; ++r) {
                        const int row = bm + wm + mt * 16 + kg * 4 + r;
                        const int b = row >> 11, t = row & 2047;
                        dst[((size_t)(b * 16 + h) * 2048 + t) * 64 + d] =
                            f2bf(acc[mt][nt][r] * scale);
                    }
                }
            }
        } else {
            // unswapped; pf_build over mt-pairs -> writes vT[bh][d][t] directly
#pragma unroll
            for (int nt = 0; nt < 4; ++nt) {
                const int c = bn + wn + nt * 16 + ln15;
                const int h = (c >> 6) & 15, d = c & 63;
#pragma unroll
                for (int mp = 0; mp < 2; ++mp) {
                    const int t0 = bm + wm + mp * 32 + kg * 8;
                    const int b = t0 >> 11, t = t0 & 2047;
                    bf16x8 pf = pf_build_s(acc[2 * mp][nt], acc[2 * mp + 1][nt], 1.0f);
                    *(bf16x8*)(v_out + ((size_t)(b * 16 + h) * 64 + d) * 2048 + t) = pf;
                }
            }
        }
    }
}

// ---------------------------------------------------------------------------
// out-projection GEMM, 64x64 tile (1024 blocks = 4/CU). R10-verified; the
// 64x64 structure stays HERE only (R12: it does not transfer to QKV).
// ---------------------------------------------------------------------------
__global__ __launch_bounds__(256) void gemm_op(
    const unsigned short* __restrict__ A,
    const unsigned short* __restrict__ BT,
    const float* __restrict__ bias,
    float* __restrict__ Cf,
    int M, int N, int K)
{
    __shared__ __align__(16) unsigned short As[64 * 32];
    __shared__ __align__(16) unsigned short Bs[64 * 32];

    const int tid  = threadIdx.x;
    const int wave = tid >> 6;
    const int lane = tid & 63;
    const int ln15 = lane & 15;
    const int kg   = lane >> 4;
    const int bm = blockIdx.x * 64, bn = blockIdx.y * 64;
    const int wm = (wave >> 1) * 32, wn = (wave & 1) * 32;

    f32x4 acc[2][2];
#pragma unroll
    for (int i = 0; i < 2; ++i)
#pragma unroll
        for (int j = 0; j < 2; ++j) acc[i][j] = (f32x4){0.f, 0.f, 0.f, 0.f};

    const int sr  = wave * 16 + (lane >> 2);   // stage row 0..63
    const int scl = (lane & 3) * 8;

    for (int k0 = 0; k0 < K; k0 += 32) {
        gl_lds16(A  + (size_t)(bm + sr) * K + k0 + scl, As + wave * 512);
        gl_lds16(BT + (size_t)(bn + sr) * K + k0 + scl, Bs + wave * 512);
        __syncthreads();

        bf16x8 af[2], bw[2];
#pragma unroll
        for (int mt = 0; mt < 2; ++mt)
            af[mt] = *(const bf16x8*)&As[(wm + mt * 16 + ln15) * 32 + kg * 8];
#pragma unroll
        for (int nt = 0; nt < 2; ++nt)
            bw[nt] = *(const bf16x8*)&Bs[(wn + nt * 16 + ln15) * 32 + kg * 8];
#pragma unroll
        for (int mt = 0; mt < 2; ++mt)
#pragma unroll
            for (int nt = 0; nt < 2; ++nt)
                acc[mt][nt] = __builtin_amdgcn_mfma_f32_16x16x32_bf16(
                    bw[nt], af[mt], acc[mt][nt], 0, 0, 0);
        __syncthreads();
    }

    // swapped: acc[mt][nt][r] = C[row=bm+wm+mt*16+ln15][col=bn+wn+nt*16+kg*4+r]
#pragma unroll
    for (int mt = 0; mt < 2; ++mt) {
        const int row = bm + wm + mt * 16 + ln15;
#pragma unroll
        for (int nt = 0; nt < 2; ++nt) {
            const int c0 = bn + wn + nt * 16 + kg * 4;
            f32x4 bv = *(const f32x4*)(bias + c0);
            f32x4 o;
#pragma unroll
            for (int r = 0; r < 4; ++r) o[r] = acc[mt][nt][r] + bv[r];
            *(f32x4*)(Cf + (size_t)row * N + c0) = o;
        }
    }
}

// mask (diagonal block) + exp + in-register transpose + row-sum accumulate
__device__ __forceinline__ void softmax_tile(
    f32x4 sr[4], bool diag, int q_loc, int kg,
    bf16x8& pf0, bf16x8& pf1, f32x4& accl, bf16x8 ones)
{
    if (diag) {
#pragma unroll
        for (int kt = 0; kt < 4; ++kt)
#pragma unroll
            for (int r = 0; r < 4; ++r)
                if (kt * 16 + kg * 4 + r > q_loc) sr[kt][r] = -1e30f;
    }
    f32x4 pe[4];
#pragma unroll
    for (int kt = 0; kt < 4; ++kt)
#pragma unroll
        for (int r = 0; r < 4; ++r) pe[kt][r] = __expf(sr[kt][r]);
    pf0 = pf_build_s(pe[0], pe[1], 1.0f);
    pf1 = pf_build_s(pe[2], pe[3], 1.0f);
    accl = __builtin_amdgcn_mfma_f32_16x16x32_bf16(pf0, ones, accl, 0, 0, 0);
    accl = __builtin_amdgcn_mfma_f32_16x16x32_bf16(pf1, ones, accl, 0, 0, 0);
}

// ---------------------------------------------------------------------------
// MFMA flash attention v6+T5 (causal). LOOP FROZEN -- exact R8/R10-verified
// iteration; R11 XCD-locality block remap kept (FETCH 55 -> 12.4 MB).
// Paired strips (sA, sB=31-sA, 33 iters balanced); K/V staged once, shared;
// double-buffered LDS; ONE barrier/iter; register prefetch; swapped QK^T +
// in-register P transpose; s_setprio(1) around MFMA clusters.
// ---------------------------------------------------------------------------
__global__ __launch_bounds__(256) void flash_attn(
    const unsigned short* __restrict__ Q,
    const unsigned short* __restrict__ Km,
    const unsigned short* __restrict__ Vtg,
    unsigned short* __restrict__ O,
    int T, int H)
{
    __shared__ __align__(16) unsigned short Ks[2][64][72];   // [buf][key][d]
    __shared__ __align__(16) unsigned short Vs[2][64][72];   // [buf][d][key]

    const int tid  = threadIdx.x;
    const int wave = tid >> 6;
    const int lane = tid & 63;
    const int ln15 = lane & 15;
    const int kg   = lane >> 4;

    // XCD-locality remap: flat -> (xcd, slot); 4 heads per XCD, 16 strips each
    const int flat = blockIdx.y * gridDim.x + blockIdx.x;   // 0..511
    const int xcd  = flat & 7;
    const int slot = flat >> 3;                             // 0..63
    const int bh   = xcd * 4 + (slot >> 4);                 // 0..31
    const int sA   = slot & 15;                             // 0..15

    const int sB   = (T >> 6) - 1 - sA;       // 31..16
    const int kmax = sB;
    const int b    = bh >> 4, h = bh & 15;
    const size_t base  = (size_t)bh * T * 64;
    const size_t vbase = (size_t)bh * 64 * T;
    const int q_loc = wave * 16 + ln15;       // query row within strip

    bf16x8 qf[2][2];
    {
        const unsigned short* QrA = Q + base + (size_t)(sA * 64 + q_loc) * 64;
        const unsigned short* QrB = Q + base + (size_t)(sB * 64 + q_loc) * 64;
        qf[0][0] = *(const bf16x8*)(QrA + kg * 8);
        qf[0][1] = *(const bf16x8*)(QrA + 32 + kg * 8);
        qf[1][0] = *(const bf16x8*)(QrB + kg * 8);
        qf[1][1] = *(const bf16x8*)(QrB + 32 + kg * 8);
    }

    bf16x8 ones;
    {
        const short o = (ln15 == 0) ? (short)0x3F80 : (short)0;
#pragma unroll
        for (int j = 0; j < 8; ++j) ones[j] = o;
    }

    f32x4 o_acc[2][4];
#pragma unroll
    for (int s = 0; s < 2; ++s)
#pragma unroll
        for (int dt = 0; dt < 4; ++dt) o_acc[s][dt] = (f32x4){0.f, 0.f, 0.f, 0.f};
    f32x4 acc_l[2] = {(f32x4){0.f, 0.f, 0.f, 0.f}, (f32x4){0.f, 0.f, 0.f, 0.f}};

    const int sky = tid >> 3;             // 0..31
    const int sd  = (tid & 7) * 8;

    bf16x8 pk0, pk1, pv0, pv1;
    pk0 = *(const bf16x8*)(Km + base + (size_t)sky * 64 + sd);
    pk1 = *(const bf16x8*)(Km + base + (size_t)(sky + 32) * 64 + sd);
    pv0 = *(const bf16x8*)(Vtg + vbase + (size_t)sky * T + sd);
    pv1 = *(const bf16x8*)(Vtg + vbase + (size_t)(sky + 32) * T + sd);

    for (int kb = 0; kb <= kmax; ++kb) {
        const int bufi = kb & 1;
        *(bf16x8*)&Ks[bufi][sky][sd]      = pk0;
        *(bf16x8*)&Ks[bufi][sky + 32][sd] = pk1;
        *(bf16x8*)&Vs[bufi][sky][sd]      = pv0;
        *(bf16x8*)&Vs[bufi][sky + 32][sd] = pv1;
        if (kb < kmax) {
            const int kn = (kb + 1) * 64;
            pk0 = *(const bf16x8*)(Km + base + (size_t)(kn + sky) * 64 + sd);
            pk1 = *(const bf16x8*)(Km + base + (size_t)(kn + sky + 32) * 64 + sd);
            pv0 = *(const bf16x8*)(Vtg + vbase + (size_t)sky * T + kn + sd);
            pv1 = *(const bf16x8*)(Vtg + vbase + (size_t)(sky + 32) * T + kn + sd);
        }
        __syncthreads();

        const bool doA = (kb <= sA);

        f32x4 srB[4], srA[4];
        __builtin_amdgcn_s_setprio(1);
#pragma unroll
        for (int kt = 0; kt < 4; ++kt) {
            bf16x8 kf0 = *(const bf16x8*)&Ks[bufi][kt * 16 + ln15][kg * 8];
            bf16x8 kf1 = *(const bf16x8*)&Ks[bufi][kt * 16 + ln15][32 + kg * 8];
            f32x4 a = (f32x4){0.f, 0.f, 0.f, 0.f};
            a = __builtin_amdgcn_mfma_f32_16x16x32_bf16(kf0, qf[1][0], a, 0, 0, 0);
            a = __builtin_amdgcn_mfma_f32_16x16x32_bf16(kf1, qf[1][1], a, 0, 0, 0);
            srB[kt] = a;
            if (doA) {
                f32x4 c = (f32x4){0.f, 0.f, 0.f, 0.f};
                c = __builtin_amdgcn_mfma_f32_16x16x32_bf16(kf0, qf[0][0], c, 0, 0, 0);
                c = __builtin_amdgcn_mfma_f32_16x16x32_bf16(kf1, qf[0][1], c, 0, 0, 0);
                srA[kt] = c;
            }
        }
        __builtin_amdgcn_s_setprio(0);

        bf16x8 pfB0, pfB1, pfA0, pfA1;
        softmax_tile(srB, kb == sB, q_loc, kg, pfB0, pfB1, acc_l[1], ones);
        if (doA)
            softmax_tile(srA, kb == sA, q_loc, kg, pfA0, pfA1, acc_l[0], ones);

        __builtin_amdgcn_s_setprio(1);
#pragma unroll
        for (int dt = 0; dt < 4; ++dt) {
            bf16x8 vf0 = *(const bf16x8*)&Vs[bufi][dt * 16 + ln15][kg * 8];
            bf16x8 vf1 = *(const bf16x8*)&Vs[bufi][dt * 16 + ln15][32 + kg * 8];
            o_acc[1][dt] = __builtin_amdgcn_mfma_f32_16x16x32_bf16(pfB0, vf0, o_acc[1][dt], 0, 0, 0);
            o_acc[1][dt] = __builtin_amdgcn_mfma_f32_16x16x32_bf16(pfB1, vf1, o_acc[1][dt], 0, 0, 0);
            if (doA) {
                o_acc[0][dt] = __builtin_amdgcn_mfma_f32_16x16x32_bf16(pfA0, vf0, o_acc[0][dt], 0, 0, 0);
                o_acc[0][dt] = __builtin_amdgcn_mfma_f32_16x16x32_bf16(pfA1, vf1, o_acc[0][dt], 0, 0, 0);
            }
        }
        __builtin_amdgcn_s_setprio(0);
    }

    // normalize; l for row kg*4+r sits in lane kg*16 (col 0)
#pragma unroll
    for (int s = 0; s < 2; ++s) {
        const int qb = (s == 0 ? sA : sB) * 64;
        float inv[4];
#pragma unroll
        for (int r = 0; r < 4; ++r)
            inv[r] = 1.0f / __shfl(acc_l[s][r], lane & 48, 64);
#pragma unroll
        for (int dt = 0; dt < 4; ++dt)
#pragma unroll
            for (int r = 0; r < 4; ++r) {
                const int t = qb + wave * 16 + kg * 4 + r;
                const int d = dt * 16 + ln15;
                O[(size_t)(b * T + t) * (H * 64) + h * 64 + d] =
                    f2bf(o_acc[s][dt][r] * inv[r]);
            }
    }
}

extern "C" void kernel_launch(void* const* d_in, const int* in_sizes, int n_in,
                              void* d_out, int out_size, void* d_ws, size_t ws_size,
                              hipStream_t stream)
{
    const int B = 2, T = 2048, E = 1024, H = 16;
    const int M = B * T;  // 4096

    const float* x  = (const float*)d_in[0];
    const float* Wq = (const float*)d_in[1];
    const float* Wk = (const float*)d_in[2];
    const float* Wv = (const float*)d_in[3];
    const float* Wo = (const float*)d_in[4];
    const float* bo = (const float*)d_in[5];
    float* out = (float*)d_out;

    // workspace (bf16): xb 8MB, WqkvT 6MB, WoT 2MB, q/k/vT 8MB x3, ao 8MB
    unsigned short* xb     = (unsigned short*)d_ws;
    unsigned short* WqkvT  = xb + (size_t)M * E;            // [3072][1024]
    unsigned short* WoT    = WqkvT + (size_t)3 * E * E;     // [1024][1024]
    unsigned short* q      = WoT + (size_t)E * E;           // [BH][T][64]
    unsigned short* k      = q + (size_t)M * E;
    unsigned short* vT     = k + (size_t)M * E;             // [BH][64][T]
    unsigned short* ao     = vT + (size_t)M * E;            // [M][E]

    // fused convert + 4x weight transpose (1 launch)
    prep<<<8192, 256, 0, stream>>>(x, Wq, Wk, Wv, Wo, xb, WqkvT, WoT);

    // fused QKV projection: [4096,1024] @ [1024,3072]; V written transposed
    dim3 g1(M / 128, 3 * E / 128);
    gemm128<1><<<g1, 256, 0, stream>>>(xb, WqkvT, nullptr, nullptr, q, k, vT,
                                       M, 3 * E, E);

    // flash attention: 512 blocks, XCD-locality remapped (frozen v6+T5 loop)
    dim3 ag(T / 128, B * H);
    flash_attn<<<ag, 256, 0, stream>>>(q, k, vT, ao, T, H);

    // out-projection: 64x64 tiles -> 1024 blocks = 4/CU
    dim3 g2(M / 64, E / 64);
    gemm_op<<<g2, 256, 0, stream>>>(ao, WoT, bo, out, M, E, E);
}